// Round 9
// baseline (756.739 us; speedup 1.0000x reference)
//
#include <hip/hip_runtime.h>

// ---------------------------------------------------------------------------
// Interaction (NequIP-style Cartesian TP message passing), MI355X.
// R9: k_main inner loop batches TWO 16-edge tiles per iteration (whole avg
// node per iteration): 2x gather ILP per wave. uhi loaded lazily inside the
// sg>=2 branches (same cache line as ulo). k_mlp/linear_up/CSR as R8.
// ---------------------------------------------------------------------------

#define NN 8000
#define NE 256000
#define OFF1 512000       // N*C
#define OFF2 2048000      // N*C + N*C*3

typedef __attribute__((ext_vector_type(8))) short short8;
typedef __attribute__((ext_vector_type(4))) float f32x4;
typedef __attribute__((ext_vector_type(2))) unsigned int uint2v;

__device__ __forceinline__ float silu_f(float x) {
    return x / (1.f + __expf(-x));
}
__device__ __forceinline__ unsigned short f2bf(float x) {
    unsigned int u = __float_as_uint(x);
    u += 0x7fff + ((u >> 16) & 1);     // round-to-nearest-even
    return (unsigned short)(u >> 16);
}
__device__ __forceinline__ float bf2f(short x) {
    return __uint_as_float(((unsigned int)(unsigned short)x) << 16);
}

// ---------------- CSR build ----------------
__global__ void k_count(const int* __restrict__ ei, int* __restrict__ counts) {
    int e = blockIdx.x * 256 + threadIdx.x;
    if (e < NE) atomicAdd(&counts[ei[NE + e]], 1);
}

__global__ __launch_bounds__(1024) void k_scan(const int* __restrict__ counts,
                                               int* __restrict__ row_ptr,
                                               int* __restrict__ cursor) {
    __shared__ int ssum[1024];
    int tid = threadIdx.x;
    int base = tid * 8;
    int v[8];
    int s = 0;
#pragma unroll
    for (int i = 0; i < 8; ++i) {
        int g = base + i;
        int x = (g < NN) ? counts[g] : 0;
        v[i] = s;
        s += x;
    }
    ssum[tid] = s;
    __syncthreads();
    for (int off = 1; off < 1024; off <<= 1) {
        int t = (tid >= off) ? ssum[tid - off] : 0;
        __syncthreads();
        ssum[tid] += t;
        __syncthreads();
    }
    int excl = ssum[tid] - s;
#pragma unroll
    for (int i = 0; i < 8; ++i) {
        int g = base + i;
        if (g < NN) {
            int val = excl + v[i];
            row_ptr[g] = val;
            cursor[g]  = val;
        }
    }
    if (tid == 0) row_ptr[NN] = NE;
}

__global__ void k_scatter(const int* __restrict__ ei, int* __restrict__ cursor,
                          int* __restrict__ sorted_eid) {
    int e = blockIdx.x * 256 + threadIdx.x;
    if (e < NE) {
        int pos = atomicAdd(&cursor[ei[NE + e]], 1);
        sorted_eid[pos] = e;
    }
}

// ---------------- Wr3T prep: wr3t[n][h] = bf16(Wr3[h][n]) ----------------
__global__ void k_wr3t(const float* __restrict__ Wr3,
                       unsigned short* __restrict__ wr3t) {
    int idx = blockIdx.x * 256 + threadIdx.x;
    if (idx >= 704 * 64) return;
    int n = idx >> 6, h = idx & 63;
    wr3t[idx] = f2bf(Wr3[h * 704 + n]);
}

// ---------------- Wr1/Wr2 transpose prep: wrt[j][q] = bf16(Wr[q][j]) -------
__global__ void k_wrt(const float* __restrict__ Wr1, const float* __restrict__ Wr2,
                      unsigned short* __restrict__ wr1t,
                      unsigned short* __restrict__ wr2t) {
    int idx = blockIdx.x * 256 + threadIdx.x;
    if (idx >= 4096) return;
    int j = idx >> 6, q = idx & 63;
    wr1t[idx] = f2bf(Wr1[q * 64 + j]);
    wr2t[idx] = f2bf(Wr2[q * 64 + j]);
}

// ---------------- linear_up -> u16[n][ch][16comp] bf16 ----------------
__global__ __launch_bounds__(256) void k_linear_up(
    const float* __restrict__ t0, const float* __restrict__ t1,
    const float* __restrict__ t2, const float* __restrict__ W0,
    const float* __restrict__ W1, const float* __restrict__ W2,
    unsigned short* __restrict__ u16) {
    int lane = threadIdx.x & 63;
    int n = blockIdx.x * 4 + (threadIdx.x >> 6);
    if (n >= NN) return;
    float acc[13];
#pragma unroll
    for (int i = 0; i < 13; ++i) acc[i] = 0.f;
    const float* t0r = t0 + n * 64;
    const float* t1r = t1 + n * 192;
    const float* t2r = t2 + n * 576;
    for (int cin = 0; cin < 64; ++cin) {
        float w0 = W0[cin * 64 + lane];
        float w1 = W1[cin * 64 + lane];
        float w2 = W2[cin * 64 + lane];
        acc[0] = fmaf(t0r[cin], w0, acc[0]);
#pragma unroll
        for (int i = 0; i < 3; ++i)
            acc[1 + i] = fmaf(t1r[cin * 3 + i], w1, acc[1 + i]);
#pragma unroll
        for (int q = 0; q < 9; ++q)
            acc[4 + q] = fmaf(t2r[cin * 9 + q], w2, acc[4 + q]);
    }
    short8 lo, hi;
#pragma unroll
    for (int m = 0; m < 8; ++m) lo[m] = (short)f2bf(acc[m]);
#pragma unroll
    for (int m = 8; m < 13; ++m) hi[m - 8] = (short)f2bf(acc[m]);
    hi[5] = 0; hi[6] = 0; hi[7] = 0;
    short8* dst = (short8*)(u16 + (size_t)n * 1024 + lane * 16);
    dst[0] = lo;
    dst[1] = hi;
}

// ---------------- edge-parallel radial MLP via MFMA (sorted order) ---------
__global__ __launch_bounds__(256) void k_mlp(
    const int* __restrict__ sorted, const int* __restrict__ ei,
    const float* __restrict__ ef, const float* __restrict__ cut,
    const float* __restrict__ a0, const float* __restrict__ a1,
    const float* __restrict__ a2, const float* __restrict__ Wr0,
    const unsigned short* __restrict__ wr1t, const unsigned short* __restrict__ wr2t,
    unsigned short* __restrict__ h3s, float* __restrict__ a_s,
    int* __restrict__ src_s) {
    __shared__ __attribute__((aligned(16))) unsigned short h1[64 * 64]; // swz; later h3_l linear
    __shared__ __attribute__((aligned(16))) unsigned short h2[64 * 64]; // swz
    __shared__ int eid_l[64];
    __shared__ float cut_l[64];
    int tid = threadIdx.x;
    int c = tid & 63, sg = tid >> 6, jb = sg * 16;
    int l15 = c & 15, lg = c >> 4;
    int i0 = blockIdx.x * 64;       // NE = 4000*64 exactly

    if (tid < 64) {
        int eid = sorted[i0 + tid];
        eid_l[tid] = eid;
        src_s[i0 + tid] = ei[eid];
        cut_l[tid] = cut[eid];
    }
    __syncthreads();
    for (int idx = tid; idx < 64 * 13; idx += 256) {
        int k = idx / 13, m = idx - 13 * k;
        int eid = eid_l[k];
        float v = (m == 0) ? a0[eid]
                : (m < 4)  ? a1[(size_t)eid * 3 + (m - 1)]
                           : a2[(size_t)eid * 9 + (m - 4)];
        a_s[(size_t)(i0 + k) * 16 + m] = v;
    }
    for (int idx = tid; idx < 64 * 3; idx += 256) {
        int k = idx / 3, m = 13 + (idx - 3 * k);
        a_s[(size_t)(i0 + k) * 16 + m] = 0.f;
    }

    short8 W1f[4][2], W2f[4][2];
#pragma unroll
    for (int mt = 0; mt < 4; ++mt)
#pragma unroll
        for (int kf = 0; kf < 2; ++kf) {
            W1f[mt][kf] = *(const short8*)(wr1t + (mt * 16 + l15) * 64 + kf * 32 + lg * 8);
            W2f[mt][kf] = *(const short8*)(wr2t + (mt * 16 + l15) * 64 + kf * 32 + lg * 8);
        }

    {   // L1 fp32: thread (c, sg) -> edge c, outputs jb..jb+15; bf16 swz write
        int eid = eid_l[c];
        const float* er = ef + (size_t)eid * 8;
        float ev[8];
#pragma unroll
        for (int r = 0; r < 8; ++r) ev[r] = er[r];
        float acc[16];
#pragma unroll
        for (int j = 0; j < 16; ++j) acc[j] = 0.f;
#pragma unroll
        for (int r = 0; r < 8; ++r)
#pragma unroll
            for (int j = 0; j < 16; ++j)
                acc[j] = fmaf(ev[r], Wr0[r * 64 + jb + j], acc[j]);
        int sw = (c & 7) << 4;
#pragma unroll
        for (int g = 0; g < 4; ++g) {
            uint2v pk;
            pk[0] = (unsigned int)f2bf(silu_f(acc[4 * g]))
                  | ((unsigned int)f2bf(silu_f(acc[4 * g + 1])) << 16);
            pk[1] = (unsigned int)f2bf(silu_f(acc[4 * g + 2]))
                  | ((unsigned int)f2bf(silu_f(acc[4 * g + 3])) << 16);
            int byte = (c * 128 + (jb + 4 * g) * 2) ^ sw;
            *(uint2v*)((char*)h1 + byte) = pk;
        }
    }
    __syncthreads();

    // ---- L2: h2 = silu(h1 @ Wr1), wave sg owns edges e = sg*16+l15
    int e = sg * 16 + l15;
    int rb = e * 128;
    int sw = (e & 7) << 4;
    float cv = cut_l[e];
    {
        short8 B0 = *(const short8*)((char*)h1 + ((rb + lg * 16) ^ sw));
        short8 B1 = *(const short8*)((char*)h1 + ((rb + 64 + lg * 16) ^ sw));
        f32x4 d0 = {0.f, 0.f, 0.f, 0.f}, d1 = {0.f, 0.f, 0.f, 0.f};
        f32x4 d2 = {0.f, 0.f, 0.f, 0.f}, d3 = {0.f, 0.f, 0.f, 0.f};
        d0 = __builtin_amdgcn_mfma_f32_16x16x32_bf16(W1f[0][0], B0, d0, 0, 0, 0);
        d0 = __builtin_amdgcn_mfma_f32_16x16x32_bf16(W1f[0][1], B1, d0, 0, 0, 0);
        d1 = __builtin_amdgcn_mfma_f32_16x16x32_bf16(W1f[1][0], B0, d1, 0, 0, 0);
        d1 = __builtin_amdgcn_mfma_f32_16x16x32_bf16(W1f[1][1], B1, d1, 0, 0, 0);
        d2 = __builtin_amdgcn_mfma_f32_16x16x32_bf16(W1f[2][0], B0, d2, 0, 0, 0);
        d2 = __builtin_amdgcn_mfma_f32_16x16x32_bf16(W1f[2][1], B1, d2, 0, 0, 0);
        d3 = __builtin_amdgcn_mfma_f32_16x16x32_bf16(W1f[3][0], B0, d3, 0, 0, 0);
        d3 = __builtin_amdgcn_mfma_f32_16x16x32_bf16(W1f[3][1], B1, d3, 0, 0, 0);
        f32x4 dd[4] = {d0, d1, d2, d3};
#pragma unroll
        for (int mt = 0; mt < 4; ++mt) {
            uint2v pk;
            pk[0] = (unsigned int)f2bf(silu_f(dd[mt][0]))
                  | ((unsigned int)f2bf(silu_f(dd[mt][1])) << 16);
            pk[1] = (unsigned int)f2bf(silu_f(dd[mt][2]))
                  | ((unsigned int)f2bf(silu_f(dd[mt][3])) << 16);
            int byte = (rb + (mt * 16 + lg * 4) * 2) ^ sw;
            *(uint2v*)((char*)h2 + byte) = pk;
        }
    }
    // ---- L3 (wave-local, no barrier): h3 = silu(h2 @ Wr2) * cut
    {
        short8 B0 = *(const short8*)((char*)h2 + ((rb + lg * 16) ^ sw));
        short8 B1 = *(const short8*)((char*)h2 + ((rb + 64 + lg * 16) ^ sw));
        f32x4 d0 = {0.f, 0.f, 0.f, 0.f}, d1 = {0.f, 0.f, 0.f, 0.f};
        f32x4 d2 = {0.f, 0.f, 0.f, 0.f}, d3 = {0.f, 0.f, 0.f, 0.f};
        d0 = __builtin_amdgcn_mfma_f32_16x16x32_bf16(W2f[0][0], B0, d0, 0, 0, 0);
        d0 = __builtin_amdgcn_mfma_f32_16x16x32_bf16(W2f[0][1], B1, d0, 0, 0, 0);
        d1 = __builtin_amdgcn_mfma_f32_16x16x32_bf16(W2f[1][0], B0, d1, 0, 0, 0);
        d1 = __builtin_amdgcn_mfma_f32_16x16x32_bf16(W2f[1][1], B1, d1, 0, 0, 0);
        d2 = __builtin_amdgcn_mfma_f32_16x16x32_bf16(W2f[2][0], B0, d2, 0, 0, 0);
        d2 = __builtin_amdgcn_mfma_f32_16x16x32_bf16(W2f[2][1], B1, d2, 0, 0, 0);
        d3 = __builtin_amdgcn_mfma_f32_16x16x32_bf16(W2f[3][0], B0, d3, 0, 0, 0);
        d3 = __builtin_amdgcn_mfma_f32_16x16x32_bf16(W2f[3][1], B1, d3, 0, 0, 0);
        f32x4 dd[4] = {d0, d1, d2, d3};
#pragma unroll
        for (int mt = 0; mt < 4; ++mt) {
            uint2v pk;
            pk[0] = (unsigned int)f2bf(silu_f(dd[mt][0]) * cv)
                  | ((unsigned int)f2bf(silu_f(dd[mt][1]) * cv) << 16);
            pk[1] = (unsigned int)f2bf(silu_f(dd[mt][2]) * cv)
                  | ((unsigned int)f2bf(silu_f(dd[mt][3]) * cv) << 16);
            int byte = rb + (mt * 16 + lg * 4) * 2;   // UNswizzled
            *(uint2v*)((char*)h1 + byte) = pk;
        }
    }
    __syncthreads();
    {   // coalesced copy-out: 8KB
        short8* dst = (short8*)(h3s + (size_t)i0 * 64);
        const short8* srcp = (const short8*)h1;
#pragma unroll
        for (int i = 0; i < 2; ++i) dst[tid + 256 * i] = srcp[tid + 256 * i];
    }
}

// ---------------- per-node main kernel: W3 MFMA + TP, 2-tile batched -------
__global__ __launch_bounds__(256) void k_main(
    const unsigned short* __restrict__ u16, const int* __restrict__ row_ptr,
    const unsigned short* __restrict__ h3s, const float* __restrict__ a_s,
    const int* __restrict__ src_s, const unsigned short* __restrict__ wr3t,
    const float* __restrict__ D0, const float* __restrict__ D1,
    const float* __restrict__ D2, float* __restrict__ out) {
    __shared__ float red[4 * 13 * 64];
    __shared__ float m_l[13 * 64];

    int tid = threadIdx.x;
    int c = tid & 63;
    int sg = tid >> 6;
    int l15 = c & 15;
    int lg = c >> 4;
    int n = blockIdx.x;
    int beg = row_ptr[n], end = row_ptr[n + 1];
    int last = end - 1;

    int p0, p1, p2;
    if (sg == 0)      { p0 = 0; p1 = 3;  p2 = 8;  }
    else if (sg == 1) { p0 = 1; p1 = 4;  p2 = 7;  }
    else if (sg == 2) { p0 = 2; p1 = 9;  p2 = 6;  }
    else              { p0 = 5; p1 = 10; p2 = 10; }

    for (int cg = 0; cg < 4; ++cg) {
        int c_lane = cg * 16 + l15;
        const unsigned short* b0 = wr3t + (size_t)(p0 * 64 + c_lane) * 64 + lg * 8;
        const unsigned short* b1 = wr3t + (size_t)(p1 * 64 + c_lane) * 64 + lg * 8;
        const unsigned short* b2 = wr3t + (size_t)(p2 * 64 + c_lane) * 64 + lg * 8;
        short8 Bf00 = *(const short8*)(b0);
        short8 Bf01 = *(const short8*)(b0 + 32);
        short8 Bf10 = *(const short8*)(b1);
        short8 Bf11 = *(const short8*)(b1 + 32);
        short8 Bf20 = *(const short8*)(b2);
        short8 Bf21 = *(const short8*)(b2 + 32);

        float accm[13];
#pragma unroll
        for (int i = 0; i < 13; ++i) accm[i] = 0.f;

        for (int tb = beg; tb < end; tb += 32) {
            // ---- two sub-tiles' A-frags + u-gathers all issued together
            int rowa = min(tb + l15, last);
            int rowb = min(tb + 16 + l15, last);
            const short8* apA = (const short8*)(h3s + (size_t)rowa * 64);
            const short8* apB = (const short8*)(h3s + (size_t)rowb * 64);
            short8 Af0a = apA[lg], Af1a = apA[4 + lg];
            short8 Af0b = apB[lg], Af1b = apB[4 + lg];

            int gpc[8];
            const unsigned short* uptr[8];
            short8 ulo[8];
#pragma unroll
            for (int h = 0; h < 2; ++h)
#pragma unroll
                for (int r = 0; r < 4; ++r) {
                    int i = h * 4 + r;
                    gpc[i] = min(tb + h * 16 + lg * 4 + r, last);
                    uptr[i] = u16 + (size_t)src_s[gpc[i]] * 1024 + c_lane * 16;
                    ulo[i] = *(const short8*)uptr[i];
                }

            f32x4 wv[2][3];
#pragma unroll
            for (int h = 0; h < 2; ++h)
#pragma unroll
                for (int p = 0; p < 3; ++p) wv[h][p] = (f32x4){0.f, 0.f, 0.f, 0.f};
            wv[0][0] = __builtin_amdgcn_mfma_f32_16x16x32_bf16(Af0a, Bf00, wv[0][0], 0, 0, 0);
            wv[0][0] = __builtin_amdgcn_mfma_f32_16x16x32_bf16(Af1a, Bf01, wv[0][0], 0, 0, 0);
            wv[0][1] = __builtin_amdgcn_mfma_f32_16x16x32_bf16(Af0a, Bf10, wv[0][1], 0, 0, 0);
            wv[0][1] = __builtin_amdgcn_mfma_f32_16x16x32_bf16(Af1a, Bf11, wv[0][1], 0, 0, 0);
            wv[0][2] = __builtin_amdgcn_mfma_f32_16x16x32_bf16(Af0a, Bf20, wv[0][2], 0, 0, 0);
            wv[0][2] = __builtin_amdgcn_mfma_f32_16x16x32_bf16(Af1a, Bf21, wv[0][2], 0, 0, 0);
            wv[1][0] = __builtin_amdgcn_mfma_f32_16x16x32_bf16(Af0b, Bf00, wv[1][0], 0, 0, 0);
            wv[1][0] = __builtin_amdgcn_mfma_f32_16x16x32_bf16(Af1b, Bf01, wv[1][0], 0, 0, 0);
            wv[1][1] = __builtin_amdgcn_mfma_f32_16x16x32_bf16(Af0b, Bf10, wv[1][1], 0, 0, 0);
            wv[1][1] = __builtin_amdgcn_mfma_f32_16x16x32_bf16(Af1b, Bf11, wv[1][1], 0, 0, 0);
            wv[1][2] = __builtin_amdgcn_mfma_f32_16x16x32_bf16(Af0b, Bf20, wv[1][2], 0, 0, 0);
            wv[1][2] = __builtin_amdgcn_mfma_f32_16x16x32_bf16(Af1b, Bf21, wv[1][2], 0, 0, 0);

#pragma unroll
            for (int h = 0; h < 2; ++h) {
#pragma unroll
                for (int r = 0; r < 4; ++r) {
                    int i = h * 4 + r;
                    int eidx = tb + h * 16 + lg * 4 + r;
                    float cv = (eidx < end) ? 1.f : 0.f;   // mask padded rows
                    float w0 = wv[h][0][r] * cv;
                    float w1 = wv[h][1][r] * cv;
                    float w2 = wv[h][2][r] * cv;
                    const float* av = a_s + (size_t)gpc[i] * 16;
                    f32x4 q0 = *(const f32x4*)(av);
                    f32x4 q1 = *(const f32x4*)(av + 4);
                    f32x4 q2 = *(const f32x4*)(av + 8);
                    float q3 = av[12];
                    float ar[13] = {q0[0], q0[1], q0[2], q0[3],
                                    q1[0], q1[1], q1[2], q1[3],
                                    q2[0], q2[1], q2[2], q2[3], q3};
                    short8 ul = ulo[i];
                    if (sg == 0) {            // p0, p3, p8 (s0)
                        float s0v = bf2f(ul[0]);
                        accm[0] = fmaf(w0 * ar[0], s0v, accm[0]);
#pragma unroll
                        for (int i3 = 0; i3 < 3; ++i3)
                            accm[1 + i3] = fmaf(w1 * ar[1 + i3], s0v, accm[1 + i3]);
#pragma unroll
                        for (int q = 0; q < 9; ++q)
                            accm[4 + q] = fmaf(w2 * ar[4 + q], s0v, accm[4 + q]);
                    } else if (sg == 1) {     // p1, p4, p7 (s1)
                        float s1v[3] = { bf2f(ul[1]), bf2f(ul[2]), bf2f(ul[3]) };
                        float d = ar[1] * s1v[0] + ar[2] * s1v[1] + ar[3] * s1v[2];
                        accm[0] = fmaf(w0, d, accm[0]);
                        float a0v = ar[0];
#pragma unroll
                        for (int i3 = 0; i3 < 3; ++i3)
                            accm[1 + i3] = fmaf(w1 * a0v, s1v[i3], accm[1 + i3]);
#pragma unroll
                        for (int i3 = 0; i3 < 3; ++i3)
#pragma unroll
                            for (int j3 = 0; j3 < 3; ++j3)
                                accm[4 + 3 * i3 + j3] =
                                    fmaf(w2 * ar[1 + i3], s1v[j3], accm[4 + 3 * i3 + j3]);
                    } else if (sg == 2) {     // p2, p9, p6 (s2)
                        short8 uh = *(const short8*)(uptr[i] + 8);  // L1-hit (same line)
                        float s2v[9];
#pragma unroll
                        for (int q = 0; q < 9; ++q)
                            s2v[q] = (q < 4) ? bf2f(ul[4 + q]) : bf2f(uh[q - 4]);
                        float d = 0.f;
#pragma unroll
                        for (int q = 0; q < 9; ++q) d = fmaf(ar[4 + q], s2v[q], d);
                        accm[0] = fmaf(w0, d, accm[0]);
                        float a0v = ar[0];
#pragma unroll
                        for (int q = 0; q < 9; ++q)
                            accm[4 + q] = fmaf(w1 * a0v, s2v[q], accm[4 + q]);
#pragma unroll
                        for (int i3 = 0; i3 < 3; ++i3) {
                            float t = ar[1] * s2v[3 * i3] + ar[2] * s2v[3 * i3 + 1] +
                                      ar[3] * s2v[3 * i3 + 2];
                            accm[1 + i3] = fmaf(w2, t, accm[1 + i3]);
                        }
                    } else {                  // p5, p10 (s1, s2)
                        short8 uh = *(const short8*)(uptr[i] + 8);  // L1-hit
                        float s1v[3] = { bf2f(ul[1]), bf2f(ul[2]), bf2f(ul[3]) };
                        float s2v[9];
#pragma unroll
                        for (int q = 0; q < 9; ++q)
                            s2v[q] = (q < 4) ? bf2f(ul[4 + q]) : bf2f(uh[q - 4]);
#pragma unroll
                        for (int i3 = 0; i3 < 3; ++i3) {
                            float t = ar[4 + 3 * i3] * s1v[0] + ar[4 + 3 * i3 + 1] * s1v[1] +
                                      ar[4 + 3 * i3 + 2] * s1v[2];
                            accm[1 + i3] = fmaf(w0, t, accm[1 + i3]);
                        }
#pragma unroll
                        for (int i3 = 0; i3 < 3; ++i3)
#pragma unroll
                            for (int j3 = 0; j3 < 3; ++j3) {
                                float t = ar[4 + 3 * i3] * s2v[j3] +
                                          ar[4 + 3 * i3 + 1] * s2v[3 + j3] +
                                          ar[4 + 3 * i3 + 2] * s2v[6 + j3];
                                accm[4 + 3 * i3 + j3] = fmaf(w1, t, accm[4 + 3 * i3 + j3]);
                            }
                    }
                }
            }
        }
        // flush: lane-group reduce; lg 0 writes its cg's 16 columns
#pragma unroll
        for (int m = 0; m < 13; ++m) {
            float v = accm[m];
            v += __shfl_xor(v, 16, 64);
            v += __shfl_xor(v, 32, 64);
            if (lg == 0) red[(sg * 13 + m) * 64 + c_lane] = v;
        }
    }

    // ---- cross-sg reduce, /avg_neighbors, D-symmetrize, store
    __syncthreads();
    for (int m = sg; m < 13; m += 4) {
        float s = red[m * 64 + c] + red[(13 + m) * 64 + c] +
                  red[(26 + m) * 64 + c] + red[(39 + m) * 64 + c];
        m_l[m * 64 + c] = s * (1.f / 32.f);
    }
    __syncthreads();
    if (sg == 0) {
        out[n * 64 + c] = m_l[c] * D0[0];
    } else if (sg == 1) {
        float v0 = m_l[64 + c], v1 = m_l[128 + c], v2 = m_l[192 + c];
#pragma unroll
        for (int j = 0; j < 3; ++j) {
            float s = v0 * D1[j] + v1 * D1[3 + j] + v2 * D1[6 + j];
            out[OFF1 + (n * 64 + c) * 3 + j] = s;
        }
    } else {
        float v[9];
#pragma unroll
        for (int p = 0; p < 9; ++p) v[p] = m_l[(4 + p) * 64 + c];
        int q0 = (sg == 2) ? 0 : 5;
        int q1 = (sg == 2) ? 5 : 9;
        for (int q = q0; q < q1; ++q) {
            float s = 0.f;
#pragma unroll
            for (int p = 0; p < 9; ++p) s = fmaf(v[p], D2[p * 9 + q], s);
            out[OFF2 + (n * 64 + c) * 9 + q] = s;
        }
    }
}

// ---------------- host launch ----------------
extern "C" void kernel_launch(void* const* d_in, const int* in_sizes, int n_in,
                              void* d_out, int out_size, void* d_ws, size_t ws_size,
                              hipStream_t stream) {
    const float* t0 = (const float*)d_in[0];
    const float* t1 = (const float*)d_in[1];
    const float* t2 = (const float*)d_in[2];
    const float* a0 = (const float*)d_in[3];
    const float* a1 = (const float*)d_in[4];
    const float* a2 = (const float*)d_in[5];
    const float* ef = (const float*)d_in[6];
    const float* cut = (const float*)d_in[7];
    const float* W0 = (const float*)d_in[8];
    const float* W1 = (const float*)d_in[9];
    const float* W2 = (const float*)d_in[10];
    const float* Wr0 = (const float*)d_in[11];
    const float* Wr1 = (const float*)d_in[12];
    const float* Wr2 = (const float*)d_in[13];
    const float* Wr3 = (const float*)d_in[14];
    const float* D0 = (const float*)d_in[15];
    const float* D1 = (const float*)d_in[16];
    const float* D2 = (const float*)d_in[17];
    const int* ei = (const int*)d_in[18];
    float* out = (float*)d_out;

    // workspace layout (~67 MB):
    unsigned short* u16 = (unsigned short*)d_ws;            // [NN*1024] bf16, 16.4MB
    unsigned short* h3s = u16 + (size_t)NN * 1024;          // [NE*64]  bf16, 32.8MB
    float* a_s = (float*)(h3s + (size_t)NE * 64);           // [NE*16]  f32, 16.4MB
    int* src_s = (int*)(a_s + (size_t)NE * 16);             // [NE]
    int* counts = src_s + NE;                               // N
    int* row_ptr = counts + NN;                             // N+1
    int* cursor = row_ptr + NN + 1;                         // N
    int* sorted = cursor + NN;                              // E
    unsigned short* wr3t = (unsigned short*)(sorted + NE);  // 45056 bf16
    unsigned short* wr1t = wr3t + 45056;                    // 4096 bf16
    unsigned short* wr2t = wr1t + 4096;                     // 4096 bf16

    hipMemsetAsync(counts, 0, NN * sizeof(int), stream);
    k_count<<<(NE + 255) / 256, 256, 0, stream>>>(ei, counts);
    k_scan<<<1, 1024, 0, stream>>>(counts, row_ptr, cursor);
    k_scatter<<<(NE + 255) / 256, 256, 0, stream>>>(ei, cursor, sorted);
    k_wr3t<<<(704 * 64 + 255) / 256, 256, 0, stream>>>(Wr3, wr3t);
    k_wrt<<<16, 256, 0, stream>>>(Wr1, Wr2, wr1t, wr2t);
    k_linear_up<<<NN / 4, 256, 0, stream>>>(t0, t1, t2, W0, W1, W2, u16);
    k_mlp<<<NE / 64, 256, 0, stream>>>(sorted, ei, ef, cut, a0, a1, a2,
                                       Wr0, wr1t, wr2t, h3s, a_s, src_s);
    k_main<<<NN, 256, 0, stream>>>(u16, row_ptr, h3s, a_s, src_s, wr3t,
                                   D0, D1, D2, out);
}

// Round 11
// 588.120 us; speedup vs baseline: 1.2867x; 1.2867x over previous
//
#include <hip/hip_runtime.h>

// ---------------------------------------------------------------------------
// Interaction (NequIP-style Cartesian TP message passing), MI355X.
// R11: k_main = R8 exact body + src_s software-pipeline (prefetch next tile's
// 4 src indices -> u-row loads issue at tile top, breaking the 2-deep
// src->u gather chain). NO launch_bounds cap (R10's forced 64-VGPR cap broke
// correctness). Fused prep kernel kept (verified equivalent). Rest as R8.
// ---------------------------------------------------------------------------

#define NN 8000
#define NE 256000
#define OFF1 512000       // N*C
#define OFF2 2048000      // N*C + N*C*3

typedef __attribute__((ext_vector_type(8))) short short8;
typedef __attribute__((ext_vector_type(4))) float f32x4;
typedef __attribute__((ext_vector_type(2))) unsigned int uint2v;

__device__ __forceinline__ float silu_f(float x) {
    return x / (1.f + __expf(-x));
}
__device__ __forceinline__ unsigned short f2bf(float x) {
    unsigned int u = __float_as_uint(x);
    u += 0x7fff + ((u >> 16) & 1);     // round-to-nearest-even
    return (unsigned short)(u >> 16);
}
__device__ __forceinline__ float bf2f(short x) {
    return __uint_as_float(((unsigned int)(unsigned short)x) << 16);
}

// ---------------- fused prep: edge-count histogram + Wr3T + Wr1T/Wr2T ------
__global__ void k_prep(const int* __restrict__ ei, int* __restrict__ counts,
                       const float* __restrict__ Wr3, unsigned short* __restrict__ wr3t,
                       const float* __restrict__ Wr1, const float* __restrict__ Wr2,
                       unsigned short* __restrict__ wr1t, unsigned short* __restrict__ wr2t) {
    int b = blockIdx.x;
    if (b < 1000) {
        int e = b * 256 + threadIdx.x;
        atomicAdd(&counts[ei[NE + e]], 1);
    } else if (b < 1176) {
        int idx = (b - 1000) * 256 + threadIdx.x;
        if (idx < 704 * 64) {
            int n = idx >> 6, h = idx & 63;
            wr3t[idx] = f2bf(Wr3[h * 704 + n]);
        }
    } else {
        int idx = (b - 1176) * 256 + threadIdx.x;
        if (idx < 4096) {
            int j = idx >> 6, q = idx & 63;
            wr1t[idx] = f2bf(Wr1[q * 64 + j]);
            wr2t[idx] = f2bf(Wr2[q * 64 + j]);
        }
    }
}

__global__ __launch_bounds__(1024) void k_scan(const int* __restrict__ counts,
                                               int* __restrict__ row_ptr,
                                               int* __restrict__ cursor) {
    __shared__ int ssum[1024];
    int tid = threadIdx.x;
    int base = tid * 8;
    int v[8];
    int s = 0;
#pragma unroll
    for (int i = 0; i < 8; ++i) {
        int g = base + i;
        int x = (g < NN) ? counts[g] : 0;
        v[i] = s;
        s += x;
    }
    ssum[tid] = s;
    __syncthreads();
    for (int off = 1; off < 1024; off <<= 1) {
        int t = (tid >= off) ? ssum[tid - off] : 0;
        __syncthreads();
        ssum[tid] += t;
        __syncthreads();
    }
    int excl = ssum[tid] - s;
#pragma unroll
    for (int i = 0; i < 8; ++i) {
        int g = base + i;
        if (g < NN) {
            int val = excl + v[i];
            row_ptr[g] = val;
            cursor[g]  = val;
        }
    }
    if (tid == 0) row_ptr[NN] = NE;
}

__global__ void k_scatter(const int* __restrict__ ei, int* __restrict__ cursor,
                          int* __restrict__ sorted_eid) {
    int e = blockIdx.x * 256 + threadIdx.x;
    if (e < NE) {
        int pos = atomicAdd(&cursor[ei[NE + e]], 1);
        sorted_eid[pos] = e;
    }
}

// ---------------- linear_up -> u16[n][ch][16comp] bf16 ----------------
__global__ __launch_bounds__(256) void k_linear_up(
    const float* __restrict__ t0, const float* __restrict__ t1,
    const float* __restrict__ t2, const float* __restrict__ W0,
    const float* __restrict__ W1, const float* __restrict__ W2,
    unsigned short* __restrict__ u16) {
    int lane = threadIdx.x & 63;
    int n = blockIdx.x * 4 + (threadIdx.x >> 6);
    if (n >= NN) return;
    float acc[13];
#pragma unroll
    for (int i = 0; i < 13; ++i) acc[i] = 0.f;
    const float* t0r = t0 + n * 64;
    const float* t1r = t1 + n * 192;
    const float* t2r = t2 + n * 576;
    for (int cin = 0; cin < 64; ++cin) {
        float w0 = W0[cin * 64 + lane];
        float w1 = W1[cin * 64 + lane];
        float w2 = W2[cin * 64 + lane];
        acc[0] = fmaf(t0r[cin], w0, acc[0]);
#pragma unroll
        for (int i = 0; i < 3; ++i)
            acc[1 + i] = fmaf(t1r[cin * 3 + i], w1, acc[1 + i]);
#pragma unroll
        for (int q = 0; q < 9; ++q)
            acc[4 + q] = fmaf(t2r[cin * 9 + q], w2, acc[4 + q]);
    }
    short8 lo, hi;
#pragma unroll
    for (int m = 0; m < 8; ++m) lo[m] = (short)f2bf(acc[m]);
#pragma unroll
    for (int m = 8; m < 13; ++m) hi[m - 8] = (short)f2bf(acc[m]);
    hi[5] = 0; hi[6] = 0; hi[7] = 0;
    short8* dst = (short8*)(u16 + (size_t)n * 1024 + lane * 16);
    dst[0] = lo;
    dst[1] = hi;
}

// ---------------- edge-parallel radial MLP via MFMA (sorted order) ---------
__global__ __launch_bounds__(256) void k_mlp(
    const int* __restrict__ sorted, const int* __restrict__ ei,
    const float* __restrict__ ef, const float* __restrict__ cut,
    const float* __restrict__ a0, const float* __restrict__ a1,
    const float* __restrict__ a2, const float* __restrict__ Wr0,
    const unsigned short* __restrict__ wr1t, const unsigned short* __restrict__ wr2t,
    unsigned short* __restrict__ h3s, float* __restrict__ a_s,
    int* __restrict__ src_s) {
    __shared__ __attribute__((aligned(16))) unsigned short h1[64 * 64]; // swz; later h3_l linear
    __shared__ __attribute__((aligned(16))) unsigned short h2[64 * 64]; // swz
    __shared__ int eid_l[64];
    __shared__ float cut_l[64];
    int tid = threadIdx.x;
    int c = tid & 63, sg = tid >> 6, jb = sg * 16;
    int l15 = c & 15, lg = c >> 4;
    int i0 = blockIdx.x * 64;       // NE = 4000*64 exactly

    if (tid < 64) {
        int eid = sorted[i0 + tid];
        eid_l[tid] = eid;
        src_s[i0 + tid] = ei[eid];
        cut_l[tid] = cut[eid];
    }
    __syncthreads();
    for (int idx = tid; idx < 64 * 13; idx += 256) {
        int k = idx / 13, m = idx - 13 * k;
        int eid = eid_l[k];
        float v = (m == 0) ? a0[eid]
                : (m < 4)  ? a1[(size_t)eid * 3 + (m - 1)]
                           : a2[(size_t)eid * 9 + (m - 4)];
        a_s[(size_t)(i0 + k) * 16 + m] = v;
    }
    for (int idx = tid; idx < 64 * 3; idx += 256) {
        int k = idx / 3, m = 13 + (idx - 3 * k);
        a_s[(size_t)(i0 + k) * 16 + m] = 0.f;
    }

    short8 W1f[4][2], W2f[4][2];
#pragma unroll
    for (int mt = 0; mt < 4; ++mt)
#pragma unroll
        for (int kf = 0; kf < 2; ++kf) {
            W1f[mt][kf] = *(const short8*)(wr1t + (mt * 16 + l15) * 64 + kf * 32 + lg * 8);
            W2f[mt][kf] = *(const short8*)(wr2t + (mt * 16 + l15) * 64 + kf * 32 + lg * 8);
        }

    {   // L1 fp32: thread (c, sg) -> edge c, outputs jb..jb+15; bf16 swz write
        int eid = eid_l[c];
        const float* er = ef + (size_t)eid * 8;
        float ev[8];
#pragma unroll
        for (int r = 0; r < 8; ++r) ev[r] = er[r];
        float acc[16];
#pragma unroll
        for (int j = 0; j < 16; ++j) acc[j] = 0.f;
#pragma unroll
        for (int r = 0; r < 8; ++r)
#pragma unroll
            for (int j = 0; j < 16; ++j)
                acc[j] = fmaf(ev[r], Wr0[r * 64 + jb + j], acc[j]);
        int sw = (c & 7) << 4;
#pragma unroll
        for (int g = 0; g < 4; ++g) {
            uint2v pk;
            pk[0] = (unsigned int)f2bf(silu_f(acc[4 * g]))
                  | ((unsigned int)f2bf(silu_f(acc[4 * g + 1])) << 16);
            pk[1] = (unsigned int)f2bf(silu_f(acc[4 * g + 2]))
                  | ((unsigned int)f2bf(silu_f(acc[4 * g + 3])) << 16);
            int byte = (c * 128 + (jb + 4 * g) * 2) ^ sw;
            *(uint2v*)((char*)h1 + byte) = pk;
        }
    }
    __syncthreads();

    // ---- L2: h2 = silu(h1 @ Wr1), wave sg owns edges e = sg*16+l15
    int e = sg * 16 + l15;
    int rb = e * 128;
    int sw = (e & 7) << 4;
    float cv = cut_l[e];
    {
        short8 B0 = *(const short8*)((char*)h1 + ((rb + lg * 16) ^ sw));
        short8 B1 = *(const short8*)((char*)h1 + ((rb + 64 + lg * 16) ^ sw));
        f32x4 d0 = {0.f, 0.f, 0.f, 0.f}, d1 = {0.f, 0.f, 0.f, 0.f};
        f32x4 d2 = {0.f, 0.f, 0.f, 0.f}, d3 = {0.f, 0.f, 0.f, 0.f};
        d0 = __builtin_amdgcn_mfma_f32_16x16x32_bf16(W1f[0][0], B0, d0, 0, 0, 0);
        d0 = __builtin_amdgcn_mfma_f32_16x16x32_bf16(W1f[0][1], B1, d0, 0, 0, 0);
        d1 = __builtin_amdgcn_mfma_f32_16x16x32_bf16(W1f[1][0], B0, d1, 0, 0, 0);
        d1 = __builtin_amdgcn_mfma_f32_16x16x32_bf16(W1f[1][1], B1, d1, 0, 0, 0);
        d2 = __builtin_amdgcn_mfma_f32_16x16x32_bf16(W1f[2][0], B0, d2, 0, 0, 0);
        d2 = __builtin_amdgcn_mfma_f32_16x16x32_bf16(W1f[2][1], B1, d2, 0, 0, 0);
        d3 = __builtin_amdgcn_mfma_f32_16x16x32_bf16(W1f[3][0], B0, d3, 0, 0, 0);
        d3 = __builtin_amdgcn_mfma_f32_16x16x32_bf16(W1f[3][1], B1, d3, 0, 0, 0);
        f32x4 dd[4] = {d0, d1, d2, d3};
#pragma unroll
        for (int mt = 0; mt < 4; ++mt) {
            uint2v pk;
            pk[0] = (unsigned int)f2bf(silu_f(dd[mt][0]))
                  | ((unsigned int)f2bf(silu_f(dd[mt][1])) << 16);
            pk[1] = (unsigned int)f2bf(silu_f(dd[mt][2]))
                  | ((unsigned int)f2bf(silu_f(dd[mt][3])) << 16);
            int byte = (rb + (mt * 16 + lg * 4) * 2) ^ sw;
            *(uint2v*)((char*)h2 + byte) = pk;
        }
    }
    // ---- L3 (wave-local, no barrier): h3 = silu(h2 @ Wr2) * cut
    {
        short8 B0 = *(const short8*)((char*)h2 + ((rb + lg * 16) ^ sw));
        short8 B1 = *(const short8*)((char*)h2 + ((rb + 64 + lg * 16) ^ sw));
        f32x4 d0 = {0.f, 0.f, 0.f, 0.f}, d1 = {0.f, 0.f, 0.f, 0.f};
        f32x4 d2 = {0.f, 0.f, 0.f, 0.f}, d3 = {0.f, 0.f, 0.f, 0.f};
        d0 = __builtin_amdgcn_mfma_f32_16x16x32_bf16(W2f[0][0], B0, d0, 0, 0, 0);
        d0 = __builtin_amdgcn_mfma_f32_16x16x32_bf16(W2f[0][1], B1, d0, 0, 0, 0);
        d1 = __builtin_amdgcn_mfma_f32_16x16x32_bf16(W2f[1][0], B0, d1, 0, 0, 0);
        d1 = __builtin_amdgcn_mfma_f32_16x16x32_bf16(W2f[1][1], B1, d1, 0, 0, 0);
        d2 = __builtin_amdgcn_mfma_f32_16x16x32_bf16(W2f[2][0], B0, d2, 0, 0, 0);
        d2 = __builtin_amdgcn_mfma_f32_16x16x32_bf16(W2f[2][1], B1, d2, 0, 0, 0);
        d3 = __builtin_amdgcn_mfma_f32_16x16x32_bf16(W2f[3][0], B0, d3, 0, 0, 0);
        d3 = __builtin_amdgcn_mfma_f32_16x16x32_bf16(W2f[3][1], B1, d3, 0, 0, 0);
        f32x4 dd[4] = {d0, d1, d2, d3};
#pragma unroll
        for (int mt = 0; mt < 4; ++mt) {
            uint2v pk;
            pk[0] = (unsigned int)f2bf(silu_f(dd[mt][0]) * cv)
                  | ((unsigned int)f2bf(silu_f(dd[mt][1]) * cv) << 16);
            pk[1] = (unsigned int)f2bf(silu_f(dd[mt][2]) * cv)
                  | ((unsigned int)f2bf(silu_f(dd[mt][3]) * cv) << 16);
            int byte = rb + (mt * 16 + lg * 4) * 2;   // UNswizzled
            *(uint2v*)((char*)h1 + byte) = pk;
        }
    }
    __syncthreads();
    {   // coalesced copy-out: 8KB
        short8* dst = (short8*)(h3s + (size_t)i0 * 64);
        const short8* srcp = (const short8*)h1;
#pragma unroll
        for (int i = 0; i < 2; ++i) dst[tid + 256 * i] = srcp[tid + 256 * i];
    }
}

// ---------------- per-node main kernel: W3 MFMA + TP (R8 + src prefetch) ---
__global__ __launch_bounds__(256) void k_main(
    const unsigned short* __restrict__ u16, const int* __restrict__ row_ptr,
    const unsigned short* __restrict__ h3s, const float* __restrict__ a_s,
    const int* __restrict__ src_s, const unsigned short* __restrict__ wr3t,
    const float* __restrict__ D0, const float* __restrict__ D1,
    const float* __restrict__ D2, float* __restrict__ out) {
    __shared__ float red[4 * 13 * 64];
    __shared__ float m_l[13 * 64];

    int tid = threadIdx.x;
    int c = tid & 63;
    int sg = tid >> 6;
    int l15 = c & 15;
    int lg = c >> 4;
    int n = blockIdx.x;
    int beg = row_ptr[n], end = row_ptr[n + 1];
    int last = end - 1;

    int p0, p1, p2;
    if (sg == 0)      { p0 = 0; p1 = 3;  p2 = 8;  }
    else if (sg == 1) { p0 = 1; p1 = 4;  p2 = 7;  }
    else if (sg == 2) { p0 = 2; p1 = 9;  p2 = 6;  }
    else              { p0 = 5; p1 = 10; p2 = 10; }

    for (int cg = 0; cg < 4; ++cg) {
        int c_lane = cg * 16 + l15;
        const unsigned short* b0 = wr3t + (size_t)(p0 * 64 + c_lane) * 64 + lg * 8;
        const unsigned short* b1 = wr3t + (size_t)(p1 * 64 + c_lane) * 64 + lg * 8;
        const unsigned short* b2 = wr3t + (size_t)(p2 * 64 + c_lane) * 64 + lg * 8;
        short8 Bf00 = *(const short8*)(b0);
        short8 Bf01 = *(const short8*)(b0 + 32);
        short8 Bf10 = *(const short8*)(b1);
        short8 Bf11 = *(const short8*)(b1 + 32);
        short8 Bf20 = *(const short8*)(b2);
        short8 Bf21 = *(const short8*)(b2 + 32);

        float accm[13];
#pragma unroll
        for (int i = 0; i < 13; ++i) accm[i] = 0.f;

        // software-pipeline: prefetch first tile's src indices
        int srcp[4];
#pragma unroll
        for (int r = 0; r < 4; ++r)
            srcp[r] = src_s[max(min(beg + lg * 4 + r, last), 0)];

        for (int tb = beg; tb < end; tb += 16) {
            int rowc = min(tb + l15, last);
            const short8* ap = (const short8*)(h3s + (size_t)rowc * 64);
            short8 Af0 = ap[lg];
            short8 Af1 = ap[4 + lg];
            int gbase = tb + lg * 4;
            int gpc[4];
            short8 ulo[4], uhi[4];
#pragma unroll
            for (int r = 0; r < 4; ++r) {
                gpc[r] = min(gbase + r, last);
                const short8* up = (const short8*)(
                    u16 + (size_t)srcp[r] * 1024 + c_lane * 16);
                ulo[r] = up[0];
                uhi[r] = up[1];
            }
            // prefetch next tile's src indices (clamped; harmless on last tile)
#pragma unroll
            for (int r = 0; r < 4; ++r)
                srcp[r] = src_s[min(tb + 16 + lg * 4 + r, last)];
            f32x4 w0v = {0.f, 0.f, 0.f, 0.f};
            f32x4 w1v = {0.f, 0.f, 0.f, 0.f};
            f32x4 w2v = {0.f, 0.f, 0.f, 0.f};
            w0v = __builtin_amdgcn_mfma_f32_16x16x32_bf16(Af0, Bf00, w0v, 0, 0, 0);
            w0v = __builtin_amdgcn_mfma_f32_16x16x32_bf16(Af1, Bf01, w0v, 0, 0, 0);
            w1v = __builtin_amdgcn_mfma_f32_16x16x32_bf16(Af0, Bf10, w1v, 0, 0, 0);
            w1v = __builtin_amdgcn_mfma_f32_16x16x32_bf16(Af1, Bf11, w1v, 0, 0, 0);
            w2v = __builtin_amdgcn_mfma_f32_16x16x32_bf16(Af0, Bf20, w2v, 0, 0, 0);
            w2v = __builtin_amdgcn_mfma_f32_16x16x32_bf16(Af1, Bf21, w2v, 0, 0, 0);
#pragma unroll
            for (int r = 0; r < 4; ++r) {
                int gp = gbase + r;
                float cv = (gp < end) ? 1.f : 0.f;   // mask padded rows
                float w0 = w0v[r] * cv;
                float w1 = w1v[r] * cv;
                float w2 = w2v[r] * cv;
                const float* av = a_s + (size_t)gpc[r] * 16;
                f32x4 q0 = *(const f32x4*)(av);
                f32x4 q1 = *(const f32x4*)(av + 4);
                f32x4 q2 = *(const f32x4*)(av + 8);
                float q3 = av[12];
                float ar[13] = {q0[0], q0[1], q0[2], q0[3],
                                q1[0], q1[1], q1[2], q1[3],
                                q2[0], q2[1], q2[2], q2[3], q3};
                if (sg == 0) {            // p0, p3, p8 (s0)
                    float s0v = bf2f(ulo[r][0]);
                    accm[0] = fmaf(w0 * ar[0], s0v, accm[0]);
#pragma unroll
                    for (int i3 = 0; i3 < 3; ++i3)
                        accm[1 + i3] = fmaf(w1 * ar[1 + i3], s0v, accm[1 + i3]);
#pragma unroll
                    for (int q = 0; q < 9; ++q)
                        accm[4 + q] = fmaf(w2 * ar[4 + q], s0v, accm[4 + q]);
                } else if (sg == 1) {     // p1, p4, p7 (s1)
                    float s1v[3] = { bf2f(ulo[r][1]), bf2f(ulo[r][2]), bf2f(ulo[r][3]) };
                    float d = ar[1] * s1v[0] + ar[2] * s1v[1] + ar[3] * s1v[2];
                    accm[0] = fmaf(w0, d, accm[0]);
                    float a0v = ar[0];
#pragma unroll
                    for (int i3 = 0; i3 < 3; ++i3)
                        accm[1 + i3] = fmaf(w1 * a0v, s1v[i3], accm[1 + i3]);
#pragma unroll
                    for (int i3 = 0; i3 < 3; ++i3)
#pragma unroll
                        for (int j3 = 0; j3 < 3; ++j3)
                            accm[4 + 3 * i3 + j3] =
                                fmaf(w2 * ar[1 + i3], s1v[j3], accm[4 + 3 * i3 + j3]);
                } else if (sg == 2) {     // p2, p9, p6 (s2)
                    float s2v[9];
#pragma unroll
                    for (int q = 0; q < 9; ++q)
                        s2v[q] = (q < 4) ? bf2f(ulo[r][4 + q]) : bf2f(uhi[r][q - 4]);
                    float d = 0.f;
#pragma unroll
                    for (int q = 0; q < 9; ++q) d = fmaf(ar[4 + q], s2v[q], d);
                    accm[0] = fmaf(w0, d, accm[0]);
                    float a0v = ar[0];
#pragma unroll
                    for (int q = 0; q < 9; ++q)
                        accm[4 + q] = fmaf(w1 * a0v, s2v[q], accm[4 + q]);
#pragma unroll
                    for (int i3 = 0; i3 < 3; ++i3) {
                        float t = ar[1] * s2v[3 * i3] + ar[2] * s2v[3 * i3 + 1] +
                                  ar[3] * s2v[3 * i3 + 2];
                        accm[1 + i3] = fmaf(w2, t, accm[1 + i3]);
                    }
                } else {                  // p5, p10 (s1, s2)
                    float s1v[3] = { bf2f(ulo[r][1]), bf2f(ulo[r][2]), bf2f(ulo[r][3]) };
                    float s2v[9];
#pragma unroll
                    for (int q = 0; q < 9; ++q)
                        s2v[q] = (q < 4) ? bf2f(ulo[r][4 + q]) : bf2f(uhi[r][q - 4]);
#pragma unroll
                    for (int i3 = 0; i3 < 3; ++i3) {
                        float t = ar[4 + 3 * i3] * s1v[0] + ar[4 + 3 * i3 + 1] * s1v[1] +
                                  ar[4 + 3 * i3 + 2] * s1v[2];
                        accm[1 + i3] = fmaf(w0, t, accm[1 + i3]);
                    }
#pragma unroll
                    for (int i3 = 0; i3 < 3; ++i3)
#pragma unroll
                        for (int j3 = 0; j3 < 3; ++j3) {
                            float t = ar[4 + 3 * i3] * s2v[j3] +
                                      ar[4 + 3 * i3 + 1] * s2v[3 + j3] +
                                      ar[4 + 3 * i3 + 2] * s2v[6 + j3];
                            accm[4 + 3 * i3 + j3] = fmaf(w1, t, accm[4 + 3 * i3 + j3]);
                        }
                }
            }
        }
        // flush: lane-group reduce; lg 0 writes its cg's 16 columns
#pragma unroll
        for (int m = 0; m < 13; ++m) {
            float v = accm[m];
            v += __shfl_xor(v, 16, 64);
            v += __shfl_xor(v, 32, 64);
            if (lg == 0) red[(sg * 13 + m) * 64 + c_lane] = v;
        }
    }

    // ---- cross-sg reduce, /avg_neighbors, D-symmetrize, store
    __syncthreads();
    for (int m = sg; m < 13; m += 4) {
        float s = red[m * 64 + c] + red[(13 + m) * 64 + c] +
                  red[(26 + m) * 64 + c] + red[(39 + m) * 64 + c];
        m_l[m * 64 + c] = s * (1.f / 32.f);
    }
    __syncthreads();
    if (sg == 0) {
        out[n * 64 + c] = m_l[c] * D0[0];
    } else if (sg == 1) {
        float v0 = m_l[64 + c], v1 = m_l[128 + c], v2 = m_l[192 + c];
#pragma unroll
        for (int j = 0; j < 3; ++j) {
            float s = v0 * D1[j] + v1 * D1[3 + j] + v2 * D1[6 + j];
            out[OFF1 + (n * 64 + c) * 3 + j] = s;
        }
    } else {
        float v[9];
#pragma unroll
        for (int p = 0; p < 9; ++p) v[p] = m_l[(4 + p) * 64 + c];
        int q0 = (sg == 2) ? 0 : 5;
        int q1 = (sg == 2) ? 5 : 9;
        for (int q = q0; q < q1; ++q) {
            float s = 0.f;
#pragma unroll
            for (int p = 0; p < 9; ++p) s = fmaf(v[p], D2[p * 9 + q], s);
            out[OFF2 + (n * 64 + c) * 9 + q] = s;
        }
    }
}

// ---------------- host launch ----------------
extern "C" void kernel_launch(void* const* d_in, const int* in_sizes, int n_in,
                              void* d_out, int out_size, void* d_ws, size_t ws_size,
                              hipStream_t stream) {
    const float* t0 = (const float*)d_in[0];
    const float* t1 = (const float*)d_in[1];
    const float* t2 = (const float*)d_in[2];
    const float* a0 = (const float*)d_in[3];
    const float* a1 = (const float*)d_in[4];
    const float* a2 = (const float*)d_in[5];
    const float* ef = (const float*)d_in[6];
    const float* cut = (const float*)d_in[7];
    const float* W0 = (const float*)d_in[8];
    const float* W1 = (const float*)d_in[9];
    const float* W2 = (const float*)d_in[10];
    const float* Wr0 = (const float*)d_in[11];
    const float* Wr1 = (const float*)d_in[12];
    const float* Wr2 = (const float*)d_in[13];
    const float* Wr3 = (const float*)d_in[14];
    const float* D0 = (const float*)d_in[15];
    const float* D1 = (const float*)d_in[16];
    const float* D2 = (const float*)d_in[17];
    const int* ei = (const int*)d_in[18];
    float* out = (float*)d_out;

    // workspace layout (~67 MB):
    unsigned short* u16 = (unsigned short*)d_ws;            // [NN*1024] bf16, 16.4MB
    unsigned short* h3s = u16 + (size_t)NN * 1024;          // [NE*64]  bf16, 32.8MB
    float* a_s = (float*)(h3s + (size_t)NE * 64);           // [NE*16]  f32, 16.4MB
    int* src_s = (int*)(a_s + (size_t)NE * 16);             // [NE]
    int* counts = src_s + NE;                               // N
    int* row_ptr = counts + NN;                             // N+1
    int* cursor = row_ptr + NN + 1;                         // N
    int* sorted = cursor + NN;                              // E
    unsigned short* wr3t = (unsigned short*)(sorted + NE);  // 45056 bf16
    unsigned short* wr1t = wr3t + 45056;                    // 4096 bf16
    unsigned short* wr2t = wr1t + 4096;                     // 4096 bf16

    hipMemsetAsync(counts, 0, NN * sizeof(int), stream);
    k_prep<<<1192, 256, 0, stream>>>(ei, counts, Wr3, wr3t, Wr1, Wr2, wr1t, wr2t);
    k_scan<<<1, 1024, 0, stream>>>(counts, row_ptr, cursor);
    k_scatter<<<(NE + 255) / 256, 256, 0, stream>>>(ei, cursor, sorted);
    k_linear_up<<<NN / 4, 256, 0, stream>>>(t0, t1, t2, W0, W1, W2, u16);
    k_mlp<<<NE / 64, 256, 0, stream>>>(sorted, ei, ef, cut, a0, a1, a2,
                                       Wr0, wr1t, wr2t, h3s, a_s, src_s);
    k_main<<<NN, 256, 0, stream>>>(u16, row_ptr, h3s, a_s, src_s, wr3t,
                                   D0, D1, D2, out);
}